// Round 3
// baseline (401.097 us; speedup 1.0000x reference)
//
#include <hip/hip_runtime.h>
#include <hip/hip_bf16.h>

// BinaryTreeLSTM  B=64, L=1024, IN_DIM=300, MEM=256 — bf16 MFMA v2.
//
// GEMM core (this round's change):
//  - A fragments loaded global->VGPR directly (plain row-major bf16, 16B chunks,
//    L2-hot). No A LDS staging at all.
//  - Only B (packed weights) staged in LDS, double-buffered via global_load_lds
//    width-16, one barrier per K-step (m97 2-phase structure).
//  - Wave tile 64 rows x 16 cols x NG gates (m-rep=4): per K-step per wave
//    NG ds_read_b128 (level: 4*12=48cy) vs 4*NG MFMA (16*5=80cy) -> MFMA-bound.
//  - B slot swizzle slot' = lq ^ ((col>>1)&3): each 16-lane quarter hits each
//    4-bank span exactly twice (2-way = free, m136).
//  - gates de-interleaved (col j = g*256+o) so gate fusion is lane-local.
//  - c carried fp32; h carried bf16 (it is the next level's GEMM input).

typedef __attribute__((ext_vector_type(8))) short bf16x8;
typedef __attribute__((ext_vector_type(4))) float f32x4;

__device__ __forceinline__ float fsig(float x)  { return 1.f / (1.f + __expf(-x)); }
__device__ __forceinline__ float ftanh(float x) { return 1.f - 2.f / (__expf(2.f * x) + 1.f); }
__device__ __forceinline__ ushort f2bf(float x) {
    __hip_bfloat16 b = __float2bfloat16(x);
    return *reinterpret_cast<ushort*>(&b);
}

__device__ __forceinline__ void gld_lds16(const void* g, void* l) {
    __builtin_amdgcn_global_load_lds((const __attribute__((address_space(1))) void*)g,
                                     (__attribute__((address_space(3))) void*)l, 16, 0, 0);
}

// ---------------- embs fp32 -> bf16 (pad K 300->320) ----------------
__global__ void conv_embs(const float* __restrict__ E, ushort* __restrict__ Eb)
{
    int tid = blockIdx.x * 256 + threadIdx.x;       // 65536*80 threads
    int row = tid / 80;
    int k = (tid - row * 80) * 4;
    float4 v = make_float4(0.f, 0.f, 0.f, 0.f);
    if (k < 300) v = *(const float4*)(E + (size_t)row * 300 + k);
    ushort4 o;
    o.x = f2bf(v.x); o.y = f2bf(v.y); o.z = f2bf(v.z); o.w = f2bf(v.w);
    *(ushort4*)(Eb + (size_t)row * 320 + k) = o;
}

// ---------------- weight pack kernels ----------------
// chunk (t, g, o, slot) holds B[k = t*32 + q*8 + e][g*256+o], q = slot ^ ((o>>1)&3)
// leaf: NG=2, NT=10 (K 300 padded to 320). elems = 10*2*256*4*8 = 163840
__global__ void pack_leaf_k(const float* __restrict__ Wcx, const float* __restrict__ Wox,
                            const float* __restrict__ bcx, const float* __restrict__ box,
                            ushort* __restrict__ Wb, float* __restrict__ bp)
{
    int idx = blockIdx.x * 256 + threadIdx.x;
    if (idx < 163840) {
        int e = idx & 7, slot = (idx >> 3) & 3, o = (idx >> 5) & 255;
        int g = (idx >> 13) & 1, t = idx >> 14;
        int q = slot ^ ((o >> 1) & 3);
        int k = t * 32 + q * 8 + e;
        float v = 0.f;
        if (k < 300) v = g ? Wox[o * 300 + k] : Wcx[o * 300 + k];
        Wb[idx] = f2bf(v);
    }
    if (idx < 512) {
        int g = idx >> 8, o = idx & 255;
        bp[idx] = g ? box[o] : bcx[o];
    }
}

// level: NG=4, NT=16 (K=512). elems = 16*4*256*4*8 = 524288
__global__ void pack_level_k(const float* __restrict__ Wl, const float* __restrict__ Wr,
                             const float* __restrict__ bl, const float* __restrict__ br,
                             ushort* __restrict__ Wb, float* __restrict__ bp)
{
    int idx = blockIdx.x * 256 + threadIdx.x;
    if (idx < 524288) {
        int e = idx & 7, slot = (idx >> 3) & 3, o = (idx >> 5) & 255;
        int g = (idx >> 13) & 3, t = idx >> 15;
        int q = slot ^ ((o >> 1) & 3);
        int k = t * 32 + q * 8 + e;
        float v = (k < 256) ? Wl[(g * 256 + o) * 256 + k]
                            : Wr[(g * 256 + o) * 256 + (k - 256)];
        Wb[idx] = f2bf(v);
    }
    if (idx < 1024) bp[idx] = bl[idx] + br[idx];
}

// ---------------- fused MFMA GEMM ----------------
// Block: 64 rows x 64 o-cols x NG gates, 256 threads = 4 waves.
// Wave wid owns cols o0 + wid*16 + lr, all 64 rows (m-rep = 4).
// MODE 0 = leaf (NG=2), 1 = level (NG=4, h->bf16), 2 = last level (h->fp32)

template<int NG, int NT, int MODE>
__global__ __launch_bounds__(256, 3)
void mfma_gemm(const ushort* __restrict__ A,     // (M, NT*32) bf16 row-major
               const ushort* __restrict__ Wb,    // packed weights
               const float* __restrict__ bp,     // (NG*256)
               const float* __restrict__ Cprev,  // (M, 512) fp32, levels only
               float* __restrict__ c_out,        // (M, 256) fp32
               ushort* __restrict__ h_out,       // (M, 256) bf16 (MODE 0/1)
               float* __restrict__ hf_out)       // (M, 256) fp32 (MODE 2)
{
    constexpr int K = NT * 32;
    __shared__ __align__(16) ushort Bs[2][NG * 2048];   // NG*256 chunks of 16B per buf

    const int tid = threadIdx.x;
    const int wid = tid >> 6, ln = tid & 63;
    const int lq = ln >> 4, lr = ln & 15;
    const int rowBlk = blockIdx.x * 64;
    const int o0 = blockIdx.y * 64;
    const int cL = wid * 16 + lr;                 // local col 0..63
    const int slotp = lq ^ ((lr >> 1) & 3);       // bank-balanced slot

    f32x4 acc[4][NG];
#pragma unroll
    for (int m = 0; m < 4; ++m)
#pragma unroll
        for (int g = 0; g < NG; ++g) acc[m][g] = f32x4{0.f, 0.f, 0.f, 0.f};

    // B staging source: chunk (t*NG + j)*1024 + o0*4 + wid*64 + ln
    const ushort* wsrc = Wb + (size_t)(o0 * 4 + wid * 64 + ln) * 8;
    // A fragment source: row = rowBlk + m*16 + lr, k-chunk lq
    const ushort* aBase = A + (size_t)rowBlk * K + (size_t)lr * K + lq * 8;

    // prologue: stage B t=0, load A t=0
#pragma unroll
    for (int j = 0; j < NG; ++j)
        gld_lds16(wsrc + (size_t)j * 1024 * 8, &Bs[0][(j * 256 + wid * 64) * 8]);

    bf16x8 a[4], an[4];
#pragma unroll
    for (int m = 0; m < 4; ++m)
        a[m] = *(const bf16x8*)(aBase + (size_t)m * 16 * K);

#pragma unroll
    for (int t = 0; t < NT; ++t) {
        __syncthreads();          // drains vmcnt (B[t] staged) + lgkmcnt (prev reads done)
        const int cur = t & 1;
        if (t + 1 < NT) {
#pragma unroll
            for (int j = 0; j < NG; ++j)
                gld_lds16(wsrc + (size_t)((t + 1) * NG + j) * 1024 * 8,
                          &Bs[cur ^ 1][(j * 256 + wid * 64) * 8]);
#pragma unroll
            for (int m = 0; m < 4; ++m)
                an[m] = *(const bf16x8*)(aBase + (size_t)m * 16 * K + (t + 1) * 32);
        }
#pragma unroll
        for (int g = 0; g < NG; ++g) {
            bf16x8 b = *(const bf16x8*)&Bs[cur][(g * 256 + cL * 4 + slotp) * 8];
#pragma unroll
            for (int m = 0; m < 4; ++m)
                acc[m][g] = __builtin_amdgcn_mfma_f32_16x16x32_bf16(a[m], b, acc[m][g], 0, 0, 0);
        }
        if (t + 1 < NT) {
#pragma unroll
            for (int m = 0; m < 4; ++m) a[m] = an[m];
        }
    }

    // epilogue: D col = lr (within 16), row = 4*lq + j
    const int col = o0 + cL;
    if constexpr (MODE == 0) {
        const float bc = bp[col], bo = bp[256 + col];
#pragma unroll
        for (int m = 0; m < 4; ++m) {
            const int row0 = rowBlk + m * 16 + lq * 4;
#pragma unroll
            for (int j = 0; j < 4; ++j) {
                int row = row0 + j;
                float cv = acc[m][0][j] + bc;
                float ov = acc[m][1][j] + bo;
                c_out[(size_t)row * 256 + col] = cv;
                h_out[(size_t)row * 256 + col] = f2bf(fsig(ov) * ftanh(cv));
            }
        }
    } else {
        const float bi  = bp[col],       blf = bp[256 + col];
        const float brf = bp[512 + col], bu  = bp[768 + col];
#pragma unroll
        for (int m = 0; m < 4; ++m) {
            const int row0 = rowBlk + m * 16 + lq * 4;
#pragma unroll
            for (int j = 0; j < 4; ++j) {
                int row = row0 + j;
                float gi = fsig(acc[m][0][j] + bi);
                float lf = fsig(acc[m][1][j] + blf);
                float rf = fsig(acc[m][2][j] + brf);
                float gu = ftanh(acc[m][3][j] + bu);
                float lc = Cprev[(size_t)row * 512 + col];
                float rc = Cprev[(size_t)row * 512 + 256 + col];
                float cv = gi * gu + lf * lc + rf * rc;
                float hv = ftanh(cv);
                c_out[(size_t)row * 256 + col] = cv;
                if constexpr (MODE == 2) hf_out[(size_t)row * 256 + col] = hv;
                else                     h_out[(size_t)row * 256 + col] = f2bf(hv);
            }
        }
    }
}

// ---------------- host ----------------

extern "C" void kernel_launch(void* const* d_in, const int* in_sizes, int n_in,
                              void* d_out, int out_size, void* d_ws, size_t ws_size,
                              hipStream_t stream)
{
    const float* embs = (const float*)d_in[0];
    const float* Wcx  = (const float*)d_in[1];
    const float* bcx  = (const float*)d_in[2];
    const float* Wox  = (const float*)d_in[3];
    const float* box  = (const float*)d_in[4];
    const float* Wl   = (const float*)d_in[5];
    const float* bl   = (const float*)d_in[6];
    const float* Wr   = (const float*)d_in[7];
    const float* br   = (const float*)d_in[8];

    char* p = (char*)d_ws;
    ushort* Wb2 = (ushort*)p;  p += (size_t)524288 * 2;
    ushort* WbL = (ushort*)p;  p += (size_t)163840 * 2;
    float*  bp2 = (float*)p;   p += 1024 * 4;
    float*  bpL = (float*)p;   p += 512 * 4;
    float*  c0  = (float*)p;   p += (size_t)65536 * 256 * 4;   // 64 MB
    ushort* h0  = (ushort*)p;  p += (size_t)65536 * 256 * 2;   // 32 MB
    char* X = p;
    ushort* embsB = (ushort*)X;                                 // 40 MB (dead after leaf)
    float*  cA = (float*)X;                                     // 32 MB
    ushort* hA = (ushort*)(X + (size_t)32768 * 256 * 4);        // 16 MB
    float*  cB = (float*)(X + (size_t)48 * 1024 * 1024);        // 16 MB
    ushort* hB = (ushort*)(X + (size_t)64 * 1024 * 1024);       // 8 MB

    conv_embs<<<20480, 256, 0, stream>>>(embs, embsB);
    pack_leaf_k<<<640, 256, 0, stream>>>(Wcx, Wox, bcx, box, WbL, bpL);
    pack_level_k<<<2048, 256, 0, stream>>>(Wl, Wr, bl, br, Wb2, bp2);

    // leaf: (65536,320) @ (320, 2*256) fused -> c0 fp32, h0 bf16
    mfma_gemm<2, 10, 0><<<dim3(1024, 4), 256, 0, stream>>>(
        embsB, WbL, bpL, nullptr, c0, h0, nullptr);

    const ushort* hin = h0;
    const float*  cin = c0;
    float*  cping[2] = {cA, cB};
    ushort* hping[2] = {hA, hB};
    int flip = 0;
    for (int np = 512; np >= 1; np >>= 1) {
        if (np == 1) {
            mfma_gemm<4, 16, 2><<<dim3(1, 4), 256, 0, stream>>>(
                hin, Wb2, bp2, cin, (float*)d_out, nullptr, (float*)d_out + 64 * 256);
        } else {
            float* co = cping[flip]; ushort* ho = hping[flip];
            mfma_gemm<4, 16, 1><<<dim3(np, 4), 256, 0, stream>>>(
                hin, Wb2, bp2, cin, co, ho, nullptr);
            cin = co; hin = ho; flip ^= 1;
        }
    }
}

// Round 4
// 367.314 us; speedup vs baseline: 1.0920x; 1.0920x over previous
//
#include <hip/hip_runtime.h>
#include <hip/hip_bf16.h>

// BinaryTreeLSTM  B=64, L=1024, IN_DIM=300, MEM=256 — bf16 MFMA v3.
//
// GEMM core: block tile 128 rows x NO o-cols x NG gates, 4 waves (2 wm x 2 wn),
// wave tile 64 rows x NO/2 o-cols x NG gates -> 32 MFMA : 12 ds_read_b128 (0.375).
// A and B both staged via global_load_lds(16B) into double-buffered LDS.
// Both-sides swizzle (linear LDS dest + inverse-swizzled per-lane global src +
// swizzled ds_read): A slot = (q + ((row>>1)&3))&3, B slot = q ^ ((o>>1)&3).
// Gates de-interleaved (col j = g*256+o), gate combine lane-local in epilogue.
// c carried fp32; h carried bf16 (next level's GEMM input).

typedef __attribute__((ext_vector_type(8))) short bf16x8;
typedef __attribute__((ext_vector_type(4))) float f32x4;

__device__ __forceinline__ float fsig(float x)  { return 1.f / (1.f + __expf(-x)); }
__device__ __forceinline__ float ftanh(float x) { return 1.f - 2.f / (__expf(2.f * x) + 1.f); }
__device__ __forceinline__ ushort f2bf(float x) {
    __hip_bfloat16 b = __float2bfloat16(x);
    return *reinterpret_cast<ushort*>(&b);
}

__device__ __forceinline__ void gld_lds16(const void* g, void* l) {
    __builtin_amdgcn_global_load_lds((const __attribute__((address_space(1))) void*)g,
                                     (__attribute__((address_space(3))) void*)l, 16, 0, 0);
}

// ---------------- embs fp32 -> bf16 (pad K 300->320) ----------------
__global__ void conv_embs(const float* __restrict__ E, ushort* __restrict__ Eb)
{
    int tid = blockIdx.x * 256 + threadIdx.x;       // 65536*80 threads
    int row = tid / 80;
    int k = (tid - row * 80) * 4;
    float4 v = make_float4(0.f, 0.f, 0.f, 0.f);
    if (k < 300) v = *(const float4*)(E + (size_t)row * 300 + k);
    ushort4 o;
    o.x = f2bf(v.x); o.y = f2bf(v.y); o.z = f2bf(v.z); o.w = f2bf(v.w);
    *(ushort4*)(Eb + (size_t)row * 320 + k) = o;
}

// ---------------- weight pack kernels ----------------
// chunk (t, g, o, slot) holds B[k = t*32 + q*8 + e][g*256+o], q = slot ^ ((o>>1)&3)
__global__ void pack_leaf_k(const float* __restrict__ Wcx, const float* __restrict__ Wox,
                            const float* __restrict__ bcx, const float* __restrict__ box,
                            ushort* __restrict__ Wb, float* __restrict__ bp)
{
    int idx = blockIdx.x * 256 + threadIdx.x;
    if (idx < 163840) {
        int e = idx & 7, slot = (idx >> 3) & 3, o = (idx >> 5) & 255;
        int g = (idx >> 13) & 1, t = idx >> 14;
        int q = slot ^ ((o >> 1) & 3);
        int k = t * 32 + q * 8 + e;
        float v = 0.f;
        if (k < 300) v = g ? Wox[o * 300 + k] : Wcx[o * 300 + k];
        Wb[idx] = f2bf(v);
    }
    if (idx < 512) {
        int g = idx >> 8, o = idx & 255;
        bp[idx] = g ? box[o] : bcx[o];
    }
}

__global__ void pack_level_k(const float* __restrict__ Wl, const float* __restrict__ Wr,
                             const float* __restrict__ bl, const float* __restrict__ br,
                             ushort* __restrict__ Wb, float* __restrict__ bp)
{
    int idx = blockIdx.x * 256 + threadIdx.x;
    if (idx < 524288) {
        int e = idx & 7, slot = (idx >> 3) & 3, o = (idx >> 5) & 255;
        int g = (idx >> 13) & 3, t = idx >> 15;
        int q = slot ^ ((o >> 1) & 3);
        int k = t * 32 + q * 8 + e;
        float v = (k < 256) ? Wl[(g * 256 + o) * 256 + k]
                            : Wr[(g * 256 + o) * 256 + (k - 256)];
        Wb[idx] = f2bf(v);
    }
    if (idx < 1024) bp[idx] = bl[idx] + br[idx];
}

// ---------------- fused MFMA GEMM ----------------
// MODE 0 = leaf (NG=2), 1 = level (h->bf16), 2 = last level (h->fp32)

template<int NG, int NT, int NO, int MODE>
__global__ __launch_bounds__(256, 2)
void mfma_gemm(const ushort* __restrict__ A,     // (M, NT*32) bf16 row-major
               const ushort* __restrict__ Wb,    // packed weights
               const float* __restrict__ bp,     // (NG*256)
               const float* __restrict__ Cprev,  // (M, 512) fp32, levels only
               float* __restrict__ c_out,        // (M, 256) fp32
               ushort* __restrict__ h_out,       // (M, 256) bf16 (MODE 0/1)
               float* __restrict__ hf_out,       // (M, 256) fp32 (MODE 2)
               int M)
{
    constexpr int K = NT * 32;
    constexpr int NN = NO / 32;                       // n-rep per wave
    __shared__ __align__(16) ushort As[2][512 * 8];   // 512 chunks = 8 KB / buf
    __shared__ __align__(16) ushort Bs[2][1024 * 8];  // 1024 chunks = 16 KB / buf

    const int tid = threadIdx.x;
    const int wid = tid >> 6, ln = tid & 63;
    const int lq = ln >> 4, lr = ln & 15;
    const int wm = wid >> 1, wn = wid & 1;
    const int rowBlk = blockIdx.x * 128;
    const int o0 = blockIdx.y * NO;

    f32x4 acc[4][NN][NG];
#pragma unroll
    for (int m = 0; m < 4; ++m)
#pragma unroll
        for (int n = 0; n < NN; ++n)
#pragma unroll
            for (int g = 0; g < NG; ++g) acc[m][n][g] = f32x4{0.f, 0.f, 0.f, 0.f};

    // ---- A staging (2 sweeps of 256 chunks): lane chunk c = s*256 + wid*64 + ln
    //      row = c>>2, slot = ln&3, stored q = (slot - ((row>>1)&3)) & 3
    const int aRow = wid * 16 + (ln >> 2);
    const int aQ = ((ln & 3) - ((ln >> 3) & 3)) & 3;
    const ushort* aSrc0 = A + (size_t)(rowBlk + aRow) * K + aQ * 8;
    const ushort* aSrc1 = A + (size_t)(rowBlk + 64 + aRow) * K + aQ * 8;

    // ---- A read swizzle: chunk(m) = (wm*64 + m*16 + lr)*4 + aSw
    const int aSw = (lq + ((lr >> 1) & 3)) & 3;
    // ---- B read swizzle: chunk(n,g) = g*(NO*4) + (wn*(NO/2) + n*16 + lr)*4 + bSw
    const int bSw = lq ^ ((lr >> 1) & 3);

    // ---- B staging: sweep s stages local chunks s*256 + wid*64 + ln
    //      g = cL/(NO*4), w = cL%(NO*4); src chunk = (t*NG+g)*1024 + o0*4 + w

    // prologue: stage t=0
    gld_lds16(aSrc0, &As[0][(wid * 64) * 8]);
    gld_lds16(aSrc1, &As[0][(256 + wid * 64) * 8]);
#pragma unroll
    for (int s = 0; s < 4; ++s) {
        const int cL = s * 256 + wid * 64 + ln;
        const int g = cL / (NO * 4), w = cL & (NO * 4 - 1);
        gld_lds16(Wb + ((size_t)g * 1024 + o0 * 4 + w) * 8,
                  &Bs[0][(s * 256 + wid * 64) * 8]);
    }

#pragma unroll
    for (int t = 0; t < NT; ++t) {
        __syncthreads();              // buf[cur] staged (vmcnt) + prev reads done (lgkm)
        const int cur = t & 1;
        if (t + 1 < NT) {
            gld_lds16(aSrc0 + (t + 1) * 32, &As[cur ^ 1][(wid * 64) * 8]);
            gld_lds16(aSrc1 + (t + 1) * 32, &As[cur ^ 1][(256 + wid * 64) * 8]);
#pragma unroll
            for (int s = 0; s < 4; ++s) {
                const int cL = s * 256 + wid * 64 + ln;
                const int g = cL / (NO * 4), w = cL & (NO * 4 - 1);
                gld_lds16(Wb + ((size_t)((t + 1) * NG + g) * 1024 + o0 * 4 + w) * 8,
                          &Bs[cur ^ 1][(s * 256 + wid * 64) * 8]);
            }
        }
        bf16x8 a[4];
#pragma unroll
        for (int m = 0; m < 4; ++m)
            a[m] = *(const bf16x8*)&As[cur][((wm * 64 + m * 16 + lr) * 4 + aSw) * 8];
#pragma unroll
        for (int n = 0; n < NN; ++n)
#pragma unroll
            for (int g = 0; g < NG; ++g) {
                bf16x8 b = *(const bf16x8*)
                    &Bs[cur][(g * (NO * 4) + (wn * (NO / 2) + n * 16 + lr) * 4 + bSw) * 8];
#pragma unroll
                for (int m = 0; m < 4; ++m)
                    acc[m][n][g] = __builtin_amdgcn_mfma_f32_16x16x32_bf16(a[m], b, acc[m][n][g], 0, 0, 0);
            }
    }

    // ---- epilogue: D col = lr (within 16), row = 4*lq + j
#pragma unroll
    for (int m = 0; m < 4; ++m) {
        const int row0 = rowBlk + wm * 64 + m * 16 + lq * 4;
#pragma unroll
        for (int n = 0; n < NN; ++n) {
            const int col = o0 + wn * (NO / 2) + n * 16 + lr;
            if constexpr (MODE == 0) {
                const float bc = bp[col], bo = bp[256 + col];
#pragma unroll
                for (int j = 0; j < 4; ++j) {
                    int row = row0 + j;
                    if (row < M) {
                        float cv = acc[m][n][0][j] + bc;
                        float ov = acc[m][n][1][j] + bo;
                        c_out[(size_t)row * 256 + col] = cv;
                        h_out[(size_t)row * 256 + col] = f2bf(fsig(ov) * ftanh(cv));
                    }
                }
            } else {
                const float bi  = bp[col],       blf = bp[256 + col];
                const float brf = bp[512 + col], bu  = bp[768 + col];
#pragma unroll
                for (int j = 0; j < 4; ++j) {
                    int row = row0 + j;
                    if (row < M) {
                        float gi = fsig(acc[m][n][0][j] + bi);
                        float lf = fsig(acc[m][n][1][j] + blf);
                        float rf = fsig(acc[m][n][2][j] + brf);
                        float gu = ftanh(acc[m][n][3][j] + bu);
                        float lc = Cprev[(size_t)row * 512 + col];
                        float rc = Cprev[(size_t)row * 512 + 256 + col];
                        float cv = gi * gu + lf * lc + rf * rc;
                        float hv = ftanh(cv);
                        c_out[(size_t)row * 256 + col] = cv;
                        if constexpr (MODE == 2) hf_out[(size_t)row * 256 + col] = hv;
                        else                     h_out[(size_t)row * 256 + col] = f2bf(hv);
                    }
                }
            }
        }
    }
}

// ---------------- host ----------------

extern "C" void kernel_launch(void* const* d_in, const int* in_sizes, int n_in,
                              void* d_out, int out_size, void* d_ws, size_t ws_size,
                              hipStream_t stream)
{
    const float* embs = (const float*)d_in[0];
    const float* Wcx  = (const float*)d_in[1];
    const float* bcx  = (const float*)d_in[2];
    const float* Wox  = (const float*)d_in[3];
    const float* box  = (const float*)d_in[4];
    const float* Wl   = (const float*)d_in[5];
    const float* bl   = (const float*)d_in[6];
    const float* Wr   = (const float*)d_in[7];
    const float* br   = (const float*)d_in[8];

    char* p = (char*)d_ws;
    ushort* Wb2 = (ushort*)p;  p += (size_t)524288 * 2;
    ushort* WbL = (ushort*)p;  p += (size_t)163840 * 2;
    float*  bp2 = (float*)p;   p += 1024 * 4;
    float*  bpL = (float*)p;   p += 512 * 4;
    float*  c0  = (float*)p;   p += (size_t)65536 * 256 * 4;   // 64 MB
    ushort* h0  = (ushort*)p;  p += (size_t)65536 * 256 * 2;   // 32 MB
    char* X = p;
    ushort* embsB = (ushort*)X;                                 // 40 MB (dead after leaf)
    float*  cA = (float*)X;                                     // 32 MB
    ushort* hA = (ushort*)(X + (size_t)32768 * 256 * 4);        // 16 MB
    float*  cB = (float*)(X + (size_t)48 * 1024 * 1024);        // 16 MB
    ushort* hB = (ushort*)(X + (size_t)64 * 1024 * 1024);       // 8 MB

    conv_embs<<<20480, 256, 0, stream>>>(embs, embsB);
    pack_leaf_k<<<640, 256, 0, stream>>>(Wcx, Wox, bcx, box, WbL, bpL);
    pack_level_k<<<2048, 256, 0, stream>>>(Wl, Wr, bl, br, Wb2, bp2);

    // leaf: (65536,320) @ (320, 2*256) -> c0 fp32, h0 bf16.  NO=128 -> grid y=2
    mfma_gemm<2, 10, 128, 0><<<dim3(512, 2), 256, 0, stream>>>(
        embsB, WbL, bpL, nullptr, c0, h0, nullptr, 65536);

    const ushort* hin = h0;
    const float*  cin = c0;
    float*  cping[2] = {cA, cB};
    ushort* hping[2] = {hA, hB};
    int flip = 0;
    for (int np = 512; np >= 1; np >>= 1) {
        if (np == 1) {
            mfma_gemm<4, 16, 64, 2><<<dim3(1, 4), 256, 0, stream>>>(
                hin, Wb2, bp2, cin, (float*)d_out, nullptr, (float*)d_out + 64 * 256, 64);
        } else {
            float* co = cping[flip]; ushort* ho = hping[flip];
            mfma_gemm<4, 16, 64, 1><<<dim3((np + 1) / 2, 4), 256, 0, stream>>>(
                hin, Wb2, bp2, cin, co, ho, nullptr, 64 * np);
            cin = co; hin = ho; flip ^= 1;
        }
    }
}